// Round 6
// baseline (396.369 us; speedup 1.0000x reference)
//
#include <hip/hip_runtime.h>
#include <cmath>

#define IMG   512
#define NPIX  25165824.0     // 32*3*512*512
#define RST   48             // hb rows per column (u16 units)
#define QSTR  (64 * RST)     // u16 per quantity block (column-major [x][r])

typedef _Float16 f16x4 __attribute__((ext_vector_type(4)));
typedef float    f32x4 __attribute__((ext_vector_type(4)));

// Gaussian band coefficient g[t] for t in [0,10], else 0. g[t] = exp(-(t-5)^2/4.5)/S
__device__ __forceinline__ _Float16 bandval(int t, float invS) {
  if (t < 0 || t > 10) return (_Float16)0.f;
  const float d = (float)(t - 5);
  return (_Float16)(__expf(-d * d * (1.0f / 4.5f)) * invS);
}

// Structure: block = 64x32 output tile, 4 waves.
// H-pass (MFMA): out[r][x] = sum_t g_t in[r][x-5+t] done as D = A_data * B_band,
//   M=16 image rows, N=16 out-x, K=2x16 in-x (window base x0-8 so loads are 16B aligned;
//   band shifted by -3 to compensate). Lane loads A[row=l%16][k=4(l/16)+i] = 4 contig floats.
//   5 quantities {x1,x2,x1^2,x2^2,x1x2} share the A-load; products formed in-register,
//   cast f16. D (col=l&15 -> x, row=4(l>>4)+e -> r) -> f16 -> column-major LDS, b64 store.
// V-pass (MFMA): out[y][c] = sum_t g_t hb[y+t][c] as D = A_band * B_data,
//   B read as 4 contiguous rows per lane from column-major LDS = one ds_read_b64.
//   SSIM map from the 5 f32 accumulators in-register; wave reduce; atomicAdd.
__global__ __launch_bounds__(256, 2)
void ssim_main(const float* __restrict__ img1, const float* __restrict__ img2,
               double* __restrict__ acc, float invS) {
  __shared__ _Float16 hb[5 * QSTR];   // 30720 B
  __shared__ float red[4];

  const int tid  = threadIdx.x;
  const int w    = tid >> 6;          // wave 0..3
  const int ln15 = tid & 15;
  const int lg   = (tid & 63) >> 4;   // lane group 0..3

  const int tx = blockIdx.x & 7;
  const int ty = blockIdx.x >> 3;
  const int xg = tx * 64;
  const int yg = ty * 32;
  const size_t plane = (size_t)blockIdx.y * (IMG * IMG);
  const float* b1 = img1 + plane;
  const float* b2 = img2 + plane;

  // Band fragments. A-frag and B-frag share the lane pattern (k=4*lg+i, m/n=ln15):
  //   H uses band as B with k-origin shifted by -3 (aligned loads), V as A unshifted.
  f16x4 bH0, bH1, bV0, bV1;
  #pragma unroll
  for (int i = 0; i < 4; i++) {
    const int kb = 4 * lg + i - ln15;
    bH0[i] = bandval(kb - 3,  invS);
    bH1[i] = bandval(kb + 13, invS);
    bV0[i] = bandval(kb,      invS);
    bV1[i] = bandval(kb + 16, invS);
  }

  const bool interior = (tx >= 1 && tx <= 6 && ty >= 1 && ty <= 14);
  const int x0 = 16 * w;   // wave's x-tile (both passes)

  // ---------------- H pass ----------------
  for (int rt = 0; rt < 3; rt++) {
    const int r0 = 16 * rt;                    // hb row-tile base (r = global y - (yg-5))
    const int grow = yg - 5 + r0 + ln15;       // global row this lane loads
    f32x4 d0 = {0.f,0.f,0.f,0.f}, d1 = d0, d2 = d0, d3 = d0, d4 = d0;
    #pragma unroll
    for (int h = 0; h < 2; h++) {
      const int gxb = xg + x0 - 8 + 16 * h + 4 * lg;   // 16B-aligned
      float av[4], bv[4];
      if (interior) {
        const f32x4 v1 = *(const f32x4*)(b1 + (size_t)grow * IMG + gxb);
        const f32x4 v2 = *(const f32x4*)(b2 + (size_t)grow * IMG + gxb);
        #pragma unroll
        for (int e = 0; e < 4; e++) { av[e] = v1[e]; bv[e] = v2[e]; }
      } else {
        const int  crow = grow < 0 ? 0 : (grow > IMG - 1 ? IMG - 1 : grow);
        const bool rok  = (unsigned)grow < (unsigned)IMG;
        #pragma unroll
        for (int e = 0; e < 4; e++) {
          const int  xi  = gxb + e;
          const int  cxi = xi < 0 ? 0 : (xi > IMG - 1 ? IMG - 1 : xi);
          const bool ok  = rok && ((unsigned)xi < (unsigned)IMG);
          av[e] = ok ? b1[(size_t)crow * IMG + cxi] : 0.f;
          bv[e] = ok ? b2[(size_t)crow * IMG + cxi] : 0.f;
        }
      }
      f16x4 fa, fb, f11, f22, f12;
      #pragma unroll
      for (int e = 0; e < 4; e++) {
        const float ax = fmaf(av[e], 0.5f, 0.5f);
        const float bx = fmaf(bv[e], 0.5f, 0.5f);
        fa[e]  = (_Float16)ax;
        fb[e]  = (_Float16)bx;
        f11[e] = (_Float16)(ax * ax);
        f22[e] = (_Float16)(bx * bx);
        f12[e] = (_Float16)(ax * bx);
      }
      const f16x4 bh = h ? bH1 : bH0;
      d0 = __builtin_amdgcn_mfma_f32_16x16x16f16(fa,  bh, d0, 0, 0, 0);
      d1 = __builtin_amdgcn_mfma_f32_16x16x16f16(fb,  bh, d1, 0, 0, 0);
      d2 = __builtin_amdgcn_mfma_f32_16x16x16f16(f11, bh, d2, 0, 0, 0);
      d3 = __builtin_amdgcn_mfma_f32_16x16x16f16(f22, bh, d3, 0, 0, 0);
      d4 = __builtin_amdgcn_mfma_f32_16x16x16f16(f12, bh, d4, 0, 0, 0);
    }
    // D: col=l&15 -> x = x0+ln15, row=4*lg+e -> r = r0+4*lg+e  (4 consecutive r)
    const int wbase = (x0 + ln15) * RST + r0 + 4 * lg;
    f16x4 s;
    #pragma unroll
    for (int e = 0; e < 4; e++) s[e] = (_Float16)d0[e];
    *(f16x4*)&hb[0 * QSTR + wbase] = s;
    #pragma unroll
    for (int e = 0; e < 4; e++) s[e] = (_Float16)d1[e];
    *(f16x4*)&hb[1 * QSTR + wbase] = s;
    #pragma unroll
    for (int e = 0; e < 4; e++) s[e] = (_Float16)d2[e];
    *(f16x4*)&hb[2 * QSTR + wbase] = s;
    #pragma unroll
    for (int e = 0; e < 4; e++) s[e] = (_Float16)d3[e];
    *(f16x4*)&hb[3 * QSTR + wbase] = s;
    #pragma unroll
    for (int e = 0; e < 4; e++) s[e] = (_Float16)d4[e];
    *(f16x4*)&hb[4 * QSTR + wbase] = s;
  }

  __syncthreads();

  // ---------------- V pass + SSIM map ----------------
  const float C1 = 1.0e-4f;
  const float C2 = 9.0e-4f;
  float ssum = 0.f;
  const int rbase = (x0 + ln15) * RST + 4 * lg;   // B: col = x0+ln15, k-rows = 4*lg+i
  #pragma unroll
  for (int yt = 0; yt < 2; yt++) {
    f32x4 e0 = {0.f,0.f,0.f,0.f}, e1 = e0, e2 = e0, e3 = e0, e4 = e0;
    #pragma unroll
    for (int h = 0; h < 2; h++) {
      const int off = rbase + 16 * yt + 16 * h;
      const f16x4 bv = h ? bV1 : bV0;
      e0 = __builtin_amdgcn_mfma_f32_16x16x16f16(bv, *(const f16x4*)&hb[0 * QSTR + off], e0, 0, 0, 0);
      e1 = __builtin_amdgcn_mfma_f32_16x16x16f16(bv, *(const f16x4*)&hb[1 * QSTR + off], e1, 0, 0, 0);
      e2 = __builtin_amdgcn_mfma_f32_16x16x16f16(bv, *(const f16x4*)&hb[2 * QSTR + off], e2, 0, 0, 0);
      e3 = __builtin_amdgcn_mfma_f32_16x16x16f16(bv, *(const f16x4*)&hb[3 * QSTR + off], e3, 0, 0, 0);
      e4 = __builtin_amdgcn_mfma_f32_16x16x16f16(bv, *(const f16x4*)&hb[4 * QSTR + off], e4, 0, 0, 0);
    }
    #pragma unroll
    for (int el = 0; el < 4; el++) {
      const float mu1 = e0[el], mu2 = e1[el];
      const float m11 = mu1 * mu1, m22 = mu2 * mu2, m12 = mu1 * mu2;
      const float s11 = e2[el] - m11;
      const float s22 = e3[el] - m22;
      const float s12 = e4[el] - m12;
      const float num = fmaf(2.f, m12, C1) * fmaf(2.f, s12, C2);
      const float den = (m11 + m22 + C1) * (s11 + s22 + C2);
      ssum += num * __builtin_amdgcn_rcpf(den);
    }
  }

  // ---------------- reduction ----------------
  #pragma unroll
  for (int m = 32; m >= 1; m >>= 1) ssum += __shfl_xor(ssum, m, 64);
  if ((tid & 63) == 0) red[w] = ssum;
  __syncthreads();
  if (tid == 0) {
    const double bs = (double)red[0] + (double)red[1] + (double)red[2] + (double)red[3];
    atomicAdd(acc, bs);
  }
}

__global__ void ssim_fin(const double* __restrict__ acc, float* __restrict__ out) {
  out[0] = 1.0f - (float)(acc[0] * (1.0 / NPIX));
}

extern "C" void kernel_launch(void* const* d_in, const int* in_sizes, int n_in,
                              void* d_out, int out_size, void* d_ws, size_t ws_size,
                              hipStream_t stream) {
  const float* img1 = (const float*)d_in[0];
  const float* img2 = (const float*)d_in[1];
  float* out = (float*)d_out;
  double* acc = (double*)d_ws;

  // ws is poisoned 0xAA before every timed launch — zero the accumulator.
  hipMemsetAsync(acc, 0, sizeof(double), stream);

  double S = 0.0;
  for (int i = 0; i < 11; i++) {
    const double x = (double)(i - 5);
    S += exp(-(x * x) / (2.0 * 1.5 * 1.5));
  }
  const float invS = (float)(1.0 / S);

  dim3 grid(128, 96);   // 8x16 tiles per plane, 96 planes
  ssim_main<<<grid, 256, 0, stream>>>(img1, img2, acc, invS);
  ssim_fin<<<1, 1, 0, stream>>>(acc, out);
}